// Round 4
// baseline (4737.992 us; speedup 1.0000x reference)
//
#include <hip/hip_runtime.h>
#include <hip/hip_fp16.h>

#define TT 8
#define NN 50000
#define EE 800000
#define HH 128
#define LL 2

typedef __attribute__((ext_vector_type(8))) short short8_t;
typedef __attribute__((ext_vector_type(4))) float f32x4;
typedef __attribute__((ext_vector_type(2))) float f32x2;

__device__ __forceinline__ float bf2f(unsigned short b){ return __uint_as_float(((unsigned)b)<<16); }
__device__ __forceinline__ unsigned short f2bf(float f){
  unsigned u = __float_as_uint(f);
  u += 0x7fffu + ((u>>16)&1u);
  return (unsigned short)(u>>16);
}
__device__ __forceinline__ float fin(float v){
  return (v == v && fabsf(v) < 1e30f) ? v : 0.0f;   // NaN/Inf -> 0
}
__device__ __forceinline__ float sigm(float x){ return 1.0f/(1.0f+__expf(-x)); }
__device__ __forceinline__ float tanh_fast(float x){
  float t = __expf(-2.0f*fabsf(x));
  float r = (1.0f-t)/(1.0f+t);
  return copysignf(r,x);
}
__device__ __forceinline__ float2 up2(unsigned v){
  __half2 a = *(__half2*)&v;
  return __half22float2(a);
}
__device__ __forceinline__ unsigned packh2(float a, float b){
  __half2 h; h.x = __float2half_rn(a); h.y = __float2half_rn(b);
  return *(unsigned*)&h;
}
// fp8 e4m3 (OCP) helpers — hardware cvt on gfx950
__device__ __forceinline__ float4 up4_fp8(unsigned v){
  f32x2 lo = __builtin_amdgcn_cvt_pk_f32_fp8(v, false);   // bytes 0,1
  f32x2 hi = __builtin_amdgcn_cvt_pk_f32_fp8(v, true);    // bytes 2,3
  return float4{lo[0], lo[1], hi[0], hi[1]};
}
__device__ __forceinline__ unsigned char f2fp8(float v){
  int w = __builtin_amdgcn_cvt_pk_fp8_f32(v, v, 0, false);
  return (unsigned char)(w & 0xFF);
}

// ---------------- dtype detection ----------------
__global__ void k_detect(const unsigned short* __restrict__ xr, int* __restrict__ flag){
  __shared__ int sm[256];
  int bad = 0;
  for (int i = threadIdx.x; i < 4096; i += 256){
    float v = bf2f(xr[i]);
    if (!(fabsf(v) < 64.0f)) bad++;
  }
  sm[threadIdx.x] = bad; __syncthreads();
  for (int off=128; off>0; off>>=1){
    if (threadIdx.x < off) sm[threadIdx.x] += sm[threadIdx.x+off];
    __syncthreads();
  }
  if (threadIdx.x == 0) flag[0] = (sm[0] > 8) ? 1 : 0;
}

// ---------------- CSR build ----------------
__global__ void k_hist(const int* __restrict__ row, int* __restrict__ counts, int E){
  int e = blockIdx.x*256 + threadIdx.x;
  if (e < E){
    int r = row[e];
    if ((unsigned)r < (unsigned)NN) atomicAdd(&counts[r], 1);
  }
}
__global__ void k_dinv(const int* __restrict__ counts, float* __restrict__ dinv, int N){
  int i = blockIdx.x*256 + threadIdx.x;
  if (i < N) dinv[i] = rsqrtf((float)counts[i] + 2.0f);
}
__global__ void k_reduce(const int* __restrict__ counts, int* __restrict__ part, int N){
  __shared__ int sm[256];
  int i = blockIdx.x*256 + threadIdx.x;
  sm[threadIdx.x] = (i < N) ? counts[i] : 0;
  __syncthreads();
  for (int off=128; off>0; off>>=1){
    if (threadIdx.x < off) sm[threadIdx.x] += sm[threadIdx.x+off];
    __syncthreads();
  }
  if (threadIdx.x == 0) part[blockIdx.x] = sm[0];
}
__global__ void k_scan_partials(const int* __restrict__ part, int* __restrict__ pscan,
                                int nb, int* __restrict__ rowptr, int N, int E){
  __shared__ int sm[256];
  int t = threadIdx.x;
  int v = (t < nb) ? part[t] : 0;
  sm[t] = v; __syncthreads();
  for (int off=1; off<256; off<<=1){
    int x = (t >= off) ? sm[t-off] : 0;
    __syncthreads();
    sm[t] += x;
    __syncthreads();
  }
  if (t < nb) pscan[t] = sm[t] - v;
  if (t == 0) rowptr[N] = E;
}
__global__ void k_scan_final(const int* __restrict__ counts, const int* __restrict__ pscan,
                             int* __restrict__ rowptr, int* __restrict__ cursor, int N){
  __shared__ int sm[256];
  int t = threadIdx.x;
  int i = blockIdx.x*256 + t;
  int v = (i < N) ? counts[i] : 0;
  sm[t] = v; __syncthreads();
  for (int off=1; off<256; off<<=1){
    int x = (t >= off) ? sm[t-off] : 0;
    __syncthreads();
    sm[t] += x;
    __syncthreads();
  }
  int ex = sm[t] - v + pscan[blockIdx.x];
  if (i < N){ rowptr[i] = ex; cursor[i] = ex; }
}
__global__ void k_fill(const int* __restrict__ row, const int* __restrict__ col,
                       int* __restrict__ cursor, const float* __restrict__ dinv,
                       int2* __restrict__ ew, int E){
  int e = blockIdx.x*256 + threadIdx.x;
  if (e < E){
    int r = row[e];
    if ((unsigned)r >= (unsigned)NN) return;
    int p = atomicAdd(&cursor[r], 1);
    if ((unsigned)p >= (unsigned)EE) return;
    int c = col[e];
    if ((unsigned)c >= (unsigned)NN) c = 0;
    ew[p] = make_int2(c, __float_as_int(dinv[c]));
  }
}
__global__ void k_h0(const void* __restrict__ h0, float* __restrict__ h,
                     const int* __restrict__ flag, int n){
  const int fl = *flag;
  int i = blockIdx.x*256 + threadIdx.x;
  if (i < n){
    float v = fl ? ((const float*)h0)[i] : bf2f(((const unsigned short*)h0)[i]);
    h[i] = fin(v);
  }
}
__global__ void k_transpose(const void* W0, const void* W1, const void* W2,
                            const void* W3, const void* W4, const void* W5,
                            unsigned short* __restrict__ Wt_hi,
                            unsigned short* __restrict__ Wt_lo,
                            const int* __restrict__ flag){
  const int fl = *flag;
  int mat = blockIdx.y;            // w*2 + l
  int wsel = mat >> 1, l = mat & 1;
  const void* W;
  switch (wsel){
    case 0: W = W0; break; case 1: W = W1; break; case 2: W = W2; break;
    case 3: W = W3; break; case 4: W = W4; break; default: W = W5; break;
  }
  int idx = blockIdx.x*256 + threadIdx.x;   // n*128 + k
  int n = idx >> 7, k = idx & 127;
  size_t src = (size_t)l*16384 + (size_t)k*128 + n;
  float v = fl ? ((const float*)W)[src] : bf2f(((const unsigned short*)W)[src]);
  v = fin(v);
  unsigned short hi = f2bf(v);
  unsigned short lo = f2bf(v - bf2f(hi));
  Wt_hi[(size_t)mat*16384 + idx] = hi;
  Wt_lo[(size_t)mat*16384 + idx] = lo;
}

// ---------------- fused z+r dual-gate GEMM -> interleaved fp8 Uzr8[N][256] ----------------
// B operands read directly from global (L2-hot 32KB weight mats) — no B-LDS.
__global__ __launch_bounds__(256) void gemm_zr(
    const void* __restrict__ S1, long s1_off, int s1_is_x,
    const float* __restrict__ S2,
    const unsigned short* __restrict__ Wz0, const unsigned short* __restrict__ Wz1,
    const unsigned short* __restrict__ Wz2, const unsigned short* __restrict__ Wz3,
    const unsigned short* __restrict__ Wr0, const unsigned short* __restrict__ Wr1,
    const unsigned short* __restrict__ Wr2, const unsigned short* __restrict__ Wr3,
    unsigned char* __restrict__ Uzr8,
    int M, const int* __restrict__ flag)
{
  __shared__ short Alds[128*72];
  const int fl = *flag;
  const int s1bf = s1_is_x && !fl;
  const int nit = fl ? 16 : 8;
  const int tid = threadIdx.x;
  const int m0 = blockIdx.x * 128;

  const int lane = tid & 63;
  const int wid  = tid >> 6;
  const int wm = (wid & 1) << 6;
  const int wn = (wid >> 1) << 6;
  const int lrow = lane & 15;
  const int lk   = (lane >> 4) << 3;

  f32x4 az[4][4], ar[4][4];
#pragma unroll
  for (int i=0;i<4;++i)
#pragma unroll
    for (int j=0;j<4;++j){ az[i][j] = f32x4{0.f,0.f,0.f,0.f}; ar[i][j] = f32x4{0.f,0.f,0.f,0.f}; }

  const int mrow = tid >> 1;
  const int hf   = tid & 1;
  int arow_g = m0 + mrow; if (arow_g >= M) arow_g = M-1;

  for (int it=0; it<nit; ++it){
    const int phase = it >> 2;              // 0:(S1,hi) 1:(S2,hi) 2:(S1,lo) 3:(S2,lo)
    const int k0 = (it & 3) * 32;
    const int koff = k0 + hf*16;
    const bool useS1 = (phase & 1) == 0;
    // ---- stage A (LDS) ----
    {
      unsigned pk[16];
      if (useS1 && s1bf){
        const unsigned short* sp = (const unsigned short*)S1 + s1_off + (size_t)arow_g*HH + koff;
        __align__(16) unsigned short tmp[16];
        *(uint4*)&tmp[0] = ((const uint4*)sp)[0];
        *(uint4*)&tmp[8] = ((const uint4*)sp)[1];
#pragma unroll
        for (int j=0;j<16;++j){
          unsigned short t = tmp[j];
          if ((t & 0x7F80u) == 0x7F80u) t = 0;
          pk[j] = (unsigned)t;
        }
      } else {
        __align__(16) float f[16];
        if (useS1){
          const float* sp = (const float*)S1 + s1_off + (size_t)arow_g*HH + koff;
          *(float4*)&f[0]  = ((const float4*)sp)[0];
          *(float4*)&f[4]  = ((const float4*)sp)[1];
          *(float4*)&f[8]  = ((const float4*)sp)[2];
          *(float4*)&f[12] = ((const float4*)sp)[3];
        } else {
          const float* sp = S2 + (size_t)arow_g*HH + koff;
          *(float4*)&f[0]  = ((const float4*)sp)[0];
          *(float4*)&f[4]  = ((const float4*)sp)[1];
          *(float4*)&f[8]  = ((const float4*)sp)[2];
          *(float4*)&f[12] = ((const float4*)sp)[3];
        }
#pragma unroll
        for (int j=0;j<16;++j){
          float v = fin(f[j]);
          unsigned short hi = f2bf(v);
          unsigned short lo = f2bf(v - bf2f(hi));
          pk[j] = (unsigned)hi | ((unsigned)lo << 16);
        }
      }
      short* arp = &Alds[mrow*72 + hf*32];
#pragma unroll
      for (int q=0;q<4;++q){
        uint4 v; v.x=pk[q*4+0]; v.y=pk[q*4+1]; v.z=pk[q*4+2]; v.w=pk[q*4+3];
        *(uint4*)(void*)(arp + q*8) = v;
      }
    }
    const unsigned short* wzp = (phase==0) ? Wz0 : (phase==1) ? Wz1 : (phase==2) ? Wz2 : Wz3;
    const unsigned short* wrp = (phase==0) ? Wr0 : (phase==1) ? Wr1 : (phase==2) ? Wr2 : Wr3;
    __syncthreads();
#pragma unroll
    for (int ks=0; ks<2; ++ks){
      short8_t af[4];
#pragma unroll
      for (int mt=0;mt<4;++mt)
        af[mt] = *(const short8_t*)&Alds[(wm + mt*16 + lrow)*72 + ks*32 + lk];
      const int kcol = k0 + ks*16 + ((lane>>4)<<2);
#pragma unroll
      for (int nt=0;nt<4;++nt){
        const int nrow = wn + nt*16 + lrow;
        uint2 wzv = *(const uint2*)(wzp + (size_t)nrow*HH + kcol);
        uint2 wrv = *(const uint2*)(wrp + (size_t)nrow*HH + kcol);
        __align__(16) unsigned bz_[4];
        __align__(16) unsigned br_[4];
        bz_[0]=(wzv.x & 0xFFFFu)*0x00010001u; bz_[1]=(wzv.x>>16)*0x00010001u;
        bz_[2]=(wzv.y & 0xFFFFu)*0x00010001u; bz_[3]=(wzv.y>>16)*0x00010001u;
        br_[0]=(wrv.x & 0xFFFFu)*0x00010001u; br_[1]=(wrv.x>>16)*0x00010001u;
        br_[2]=(wrv.y & 0xFFFFu)*0x00010001u; br_[3]=(wrv.y>>16)*0x00010001u;
        short8_t bzf = *(const short8_t*)bz_;
        short8_t brf = *(const short8_t*)br_;
#pragma unroll
        for (int mt=0;mt<4;++mt){
          az[mt][nt] = __builtin_amdgcn_mfma_f32_16x16x32_bf16(af[mt], bzf, az[mt][nt], 0, 0, 0);
          ar[mt][nt] = __builtin_amdgcn_mfma_f32_16x16x32_bf16(af[mt], brf, ar[mt][nt], 0, 0, 0);
        }
      }
    }
    __syncthreads();
  }
#pragma unroll
  for (int mt=0;mt<4;++mt){
    int rbase = m0 + wm + mt*16 + ((lane>>4)<<2);
#pragma unroll
    for (int nt=0;nt<4;++nt){
      int cc = wn + nt*16 + (lane & 15);
      f32x4 vz = az[mt][nt];
      f32x4 vr = ar[mt][nt];
#pragma unroll
      for (int r=0;r<4;++r){
        int row = rbase + r;
        if (row < M){
          Uzr8[(size_t)row*256 + cc]       = f2fp8(vz[r]);
          Uzr8[(size_t)row*256 + 128 + cc] = f2fp8(vr[r]);
        }
      }
    }
  }
}

// ---------------- single-gate GEMM (h-candidate), S2 = fp16 rhbuf ----------------
__global__ __launch_bounds__(256) void gemm_h(
    const void* __restrict__ S1, long s1_off, int s1_is_x,
    const __half* __restrict__ S2,
    const unsigned short* __restrict__ W0, const unsigned short* __restrict__ W1,
    const unsigned short* __restrict__ W2, const unsigned short* __restrict__ W3,
    __half* __restrict__ C, int M, const int* __restrict__ flag)
{
  __shared__ short Alds[128*72];
  const int fl = *flag;
  const int s1bf = s1_is_x && !fl;
  const int nit = fl ? 16 : 8;
  const int tid = threadIdx.x;
  const int m0 = blockIdx.x * 128;

  const int lane = tid & 63;
  const int wid  = tid >> 6;
  const int wm = (wid & 1) << 6;
  const int wn = (wid >> 1) << 6;
  const int lrow = lane & 15;
  const int lk   = (lane >> 4) << 3;

  f32x4 acc[4][4];
#pragma unroll
  for (int i=0;i<4;++i)
#pragma unroll
    for (int j=0;j<4;++j) acc[i][j] = f32x4{0.f,0.f,0.f,0.f};

  const int mrow = tid >> 1;
  const int hf = tid & 1;
  int arow_g = m0 + mrow; if (arow_g >= M) arow_g = M-1;

  for (int it=0; it<nit; ++it){
    const int phase = it >> 2;
    const int k0 = (it & 3) * 32;
    const int koff = k0 + hf*16;
    const bool useS1 = (phase & 1) == 0;
    {
      unsigned pk[16];
      if (useS1 && s1bf){
        const unsigned short* sp = (const unsigned short*)S1 + s1_off + (size_t)arow_g*HH + koff;
        __align__(16) unsigned short tmp[16];
        *(uint4*)&tmp[0] = ((const uint4*)sp)[0];
        *(uint4*)&tmp[8] = ((const uint4*)sp)[1];
#pragma unroll
        for (int j=0;j<16;++j){
          unsigned short t = tmp[j];
          if ((t & 0x7F80u) == 0x7F80u) t = 0;
          pk[j] = (unsigned)t;
        }
      } else {
        __align__(16) float f[16];
        if (useS1){
          const float* sp = (const float*)S1 + s1_off + (size_t)arow_g*HH + koff;
          *(float4*)&f[0]  = ((const float4*)sp)[0];
          *(float4*)&f[4]  = ((const float4*)sp)[1];
          *(float4*)&f[8]  = ((const float4*)sp)[2];
          *(float4*)&f[12] = ((const float4*)sp)[3];
        } else {
          const __half* sp = S2 + (size_t)arow_g*HH + koff;
          __align__(16) __half tmp[16];
          *(uint4*)&tmp[0] = ((const uint4*)sp)[0];
          *(uint4*)&tmp[8] = ((const uint4*)sp)[1];
#pragma unroll
          for (int j=0;j<16;++j) f[j] = __half2float(tmp[j]);
        }
#pragma unroll
        for (int j=0;j<16;++j){
          float v = fin(f[j]);
          unsigned short hi = f2bf(v);
          unsigned short lo = f2bf(v - bf2f(hi));
          pk[j] = (unsigned)hi | ((unsigned)lo << 16);
        }
      }
      short* arp = &Alds[mrow*72 + hf*32];
#pragma unroll
      for (int q=0;q<4;++q){
        uint4 v; v.x=pk[q*4+0]; v.y=pk[q*4+1]; v.z=pk[q*4+2]; v.w=pk[q*4+3];
        *(uint4*)(void*)(arp + q*8) = v;
      }
    }
    const unsigned short* wbp = (phase==0) ? W0 : (phase==1) ? W1 : (phase==2) ? W2 : W3;
    __syncthreads();
#pragma unroll
    for (int ks=0; ks<2; ++ks){
      short8_t af[4];
#pragma unroll
      for (int mt=0;mt<4;++mt)
        af[mt] = *(const short8_t*)&Alds[(wm + mt*16 + lrow)*72 + ks*32 + lk];
      const int kcol = k0 + ks*16 + ((lane>>4)<<2);
#pragma unroll
      for (int nt=0;nt<4;++nt){
        const int nrow = wn + nt*16 + lrow;
        uint2 wv = *(const uint2*)(wbp + (size_t)nrow*HH + kcol);
        __align__(16) unsigned bb_[4];
        bb_[0]=(wv.x & 0xFFFFu)*0x00010001u; bb_[1]=(wv.x>>16)*0x00010001u;
        bb_[2]=(wv.y & 0xFFFFu)*0x00010001u; bb_[3]=(wv.y>>16)*0x00010001u;
        short8_t bf_ = *(const short8_t*)bb_;
#pragma unroll
        for (int mt=0;mt<4;++mt)
          acc[mt][nt] = __builtin_amdgcn_mfma_f32_16x16x32_bf16(af[mt], bf_, acc[mt][nt], 0, 0, 0);
      }
    }
    __syncthreads();
  }
#pragma unroll
  for (int mt=0;mt<4;++mt){
    int rbase = m0 + wm + mt*16 + ((lane>>4)<<2);
#pragma unroll
    for (int nt=0;nt<4;++nt){
      int cc = wn + nt*16 + (lane & 15);
      f32x4 a = acc[mt][nt];
#pragma unroll
      for (int r=0;r<4;++r){
        int row = rbase + r;
        if (row < M) C[(size_t)row*HH + cc] = __float2half_rn(a[r]);
      }
    }
  }
}

// ---------------- fused z+r propagation (two dst nodes per wave, fp8 gather) ----------------
// Uzr8: [N][256B] fp8 = z|r. Half-wave (32 lanes) per node; lane l5 owns bytes
// 8*l5..8*l5+7 of the row (l5<16: z-ch 8*l5.., l5>=16: r-ch 8*(l5-16)..).
__global__ __launch_bounds__(256) void prop_zr(
    const unsigned char* __restrict__ Uzr8,
    const int* __restrict__ rowptr, const int2* __restrict__ ew,
    const float* __restrict__ dinv,
    const void* __restrict__ bxz, const void* __restrict__ bhz,
    const void* __restrict__ bxr, const void* __restrict__ bhr, int boff,
    const float* __restrict__ hl, __half2* __restrict__ zbuf,
    __half2* __restrict__ rhbuf, const int* __restrict__ flag, int N)
{
  const int fl = *flag;
  int lane = threadIdx.x & 63;
  int l5 = lane & 31;
  int d = (blockIdx.x << 3) + ((threadIdx.x >> 6) << 1) + (lane >> 5);
  if (d >= N) return;
  float di = dinv[d];
  const uint2* U2 = (const uint2*)Uzr8;     // 32 uint2 per row
  uint2 sv = U2[(size_t)d*32 + l5];
  float4 s0f = up4_fp8(sv.x), s1f = up4_fp8(sv.y);
  float sw = 2.0f*di;
  float4 aA = float4{sw*s0f.x, sw*s0f.y, sw*s0f.z, sw*s0f.w};
  float4 aB = float4{sw*s1f.x, sw*s1f.y, sw*s1f.z, sw*s1f.w};
  int b = rowptr[d], e = rowptr[d+1];
  if (b < 0) b = 0; if (e > EE) e = EE; if (e < b) e = b;
  for (int base=b; base<e; base+=32){
    int cnt = e - base; if (cnt > 32) cnt = 32;
    int idx = base + l5;
    int2 ev = (idx < e) ? ew[idx] : make_int2(0,0);
    int mc = ev.x; float mw = __int_as_float(ev.y);
    if ((unsigned)mc >= (unsigned)NN){ mc = 0; mw = 0.0f; }
    int j = 0;
    for (; j+7 < cnt; j += 8){
      int s0 = __shfl(mc, j,   32), s1 = __shfl(mc, j+1, 32);
      int s2 = __shfl(mc, j+2, 32), s3 = __shfl(mc, j+3, 32);
      int s4 = __shfl(mc, j+4, 32), s5 = __shfl(mc, j+5, 32);
      int s6 = __shfl(mc, j+6, 32), s7 = __shfl(mc, j+7, 32);
      float w0 = __shfl(mw, j,   32), w1 = __shfl(mw, j+1, 32);
      float w2 = __shfl(mw, j+2, 32), w3 = __shfl(mw, j+3, 32);
      float w4 = __shfl(mw, j+4, 32), w5 = __shfl(mw, j+5, 32);
      float w6 = __shfl(mw, j+6, 32), w7 = __shfl(mw, j+7, 32);
      uint2 v0 = U2[(size_t)s0*32 + l5];
      uint2 v1 = U2[(size_t)s1*32 + l5];
      uint2 v2 = U2[(size_t)s2*32 + l5];
      uint2 v3 = U2[(size_t)s3*32 + l5];
      uint2 v4 = U2[(size_t)s4*32 + l5];
      uint2 v5 = U2[(size_t)s5*32 + l5];
      uint2 v6 = U2[(size_t)s6*32 + l5];
      uint2 v7 = U2[(size_t)s7*32 + l5];
#define ACC_ZR(vv, ww) { float4 gA = up4_fp8(vv.x), gB = up4_fp8(vv.y); \
      aA.x += ww*gA.x; aA.y += ww*gA.y; aA.z += ww*gA.z; aA.w += ww*gA.w; \
      aB.x += ww*gB.x; aB.y += ww*gB.y; aB.z += ww*gB.z; aB.w += ww*gB.w; }
      ACC_ZR(v0, w0) ACC_ZR(v1, w1) ACC_ZR(v2, w2) ACC_ZR(v3, w3)
      ACC_ZR(v4, w4) ACC_ZR(v5, w5) ACC_ZR(v6, w6) ACC_ZR(v7, w7)
    }
    for (; j < cnt; ++j){
      int s = __shfl(mc, j, 32);
      float w = __shfl(mw, j, 32);
      uint2 v = U2[(size_t)s*32 + l5];
      ACC_ZR(v, w)
    }
#undef ACC_ZR
  }
  float av[8] = {aA.x, aA.y, aA.z, aA.w, aB.x, aB.y, aB.z, aB.w};
  if (l5 < 16){
    int c0 = boff + (l5 << 3);
    float g[8];
#pragma unroll
    for (int i=0;i<8;++i){
      float b1 = fl ? ((const float*)bxz)[c0+i] : bf2f(((const unsigned short*)bxz)[c0+i]);
      float b2 = fl ? ((const float*)bhz)[c0+i] : bf2f(((const unsigned short*)bhz)[c0+i]);
      g[i] = sigm(di*av[i] + fin(b1) + fin(b2));
    }
    uint4 o; o.x = packh2(g[0],g[1]); o.y = packh2(g[2],g[3]);
    o.z = packh2(g[4],g[5]); o.w = packh2(g[6],g[7]);
    ((uint4*)zbuf)[(size_t)d*16 + l5] = o;
  } else {
    int q = l5 - 16;
    int c0 = boff + (q << 3);
    float g[8];
#pragma unroll
    for (int i=0;i<8;++i){
      float b1 = fl ? ((const float*)bxr)[c0+i] : bf2f(((const unsigned short*)bxr)[c0+i]);
      float b2 = fl ? ((const float*)bhr)[c0+i] : bf2f(((const unsigned short*)bhr)[c0+i]);
      g[i] = sigm(di*av[i] + fin(b1) + fin(b2));
    }
    float4 hv0 = ((const float4*)hl)[(size_t)d*32 + 2*q];
    float4 hv1 = ((const float4*)hl)[(size_t)d*32 + 2*q + 1];
    uint4 o;
    o.x = packh2(g[0]*hv0.x, g[1]*hv0.y);
    o.y = packh2(g[2]*hv0.z, g[3]*hv0.w);
    o.z = packh2(g[4]*hv1.x, g[5]*hv1.y);
    o.w = packh2(g[6]*hv1.z, g[7]*hv1.w);
    ((uint4*)rhbuf)[(size_t)d*16 + q] = o;
  }
}

// ---------------- h-candidate propagation + state update (two nodes per wave) ----------------
// U: [N][128] fp16 (256B rows). Half-wave per node; lane l5 owns ch 4*l5..4*l5+3.
__global__ __launch_bounds__(256) void prop_h(
    const __half* __restrict__ U, const int* __restrict__ rowptr,
    const int2* __restrict__ ew, const float* __restrict__ dinv,
    const void* __restrict__ bx, const void* __restrict__ bh, int boff,
    const __half2* __restrict__ zbuf, float* __restrict__ hl,
    void* __restrict__ outbase, long out_off, int has_out,
    const int* __restrict__ flag, int N)
{
  const int fl = *flag;
  int lane = threadIdx.x & 63;
  int l5 = lane & 31;
  int d = (blockIdx.x << 3) + ((threadIdx.x >> 6) << 1) + (lane >> 5);
  if (d >= N) return;
  float di = dinv[d];
  const uint2* U2 = (const uint2*)U;    // 32 uint2 per row (4 halfs each)
  uint2 sv = U2[(size_t)d*32 + l5];
  float2 s0f = up2(sv.x), s1f = up2(sv.y);
  float sw = 2.0f*di;
  float4 a = float4{sw*s0f.x, sw*s0f.y, sw*s1f.x, sw*s1f.y};
  int b = rowptr[d], e = rowptr[d+1];
  if (b < 0) b = 0; if (e > EE) e = EE; if (e < b) e = b;
  for (int base=b; base<e; base+=32){
    int cnt = e - base; if (cnt > 32) cnt = 32;
    int idx = base + l5;
    int2 ev = (idx < e) ? ew[idx] : make_int2(0,0);
    int mc = ev.x; float mw = __int_as_float(ev.y);
    if ((unsigned)mc >= (unsigned)NN){ mc = 0; mw = 0.0f; }
    int j = 0;
    for (; j+7 < cnt; j += 8){
      int s0 = __shfl(mc, j,   32), s1 = __shfl(mc, j+1, 32);
      int s2 = __shfl(mc, j+2, 32), s3 = __shfl(mc, j+3, 32);
      int s4 = __shfl(mc, j+4, 32), s5 = __shfl(mc, j+5, 32);
      int s6 = __shfl(mc, j+6, 32), s7 = __shfl(mc, j+7, 32);
      float w0 = __shfl(mw, j,   32), w1 = __shfl(mw, j+1, 32);
      float w2 = __shfl(mw, j+2, 32), w3 = __shfl(mw, j+3, 32);
      float w4 = __shfl(mw, j+4, 32), w5 = __shfl(mw, j+5, 32);
      float w6 = __shfl(mw, j+6, 32), w7 = __shfl(mw, j+7, 32);
      uint2 v0 = U2[(size_t)s0*32 + l5];
      uint2 v1 = U2[(size_t)s1*32 + l5];
      uint2 v2 = U2[(size_t)s2*32 + l5];
      uint2 v3 = U2[(size_t)s3*32 + l5];
      uint2 v4 = U2[(size_t)s4*32 + l5];
      uint2 v5 = U2[(size_t)s5*32 + l5];
      uint2 v6 = U2[(size_t)s6*32 + l5];
      uint2 v7 = U2[(size_t)s7*32 + l5];
#define ACC_H(vv, ww) { float2 gx = up2(vv.x), gy = up2(vv.y); \
      a.x += ww*gx.x; a.y += ww*gx.y; a.z += ww*gy.x; a.w += ww*gy.y; }
      ACC_H(v0, w0) ACC_H(v1, w1) ACC_H(v2, w2) ACC_H(v3, w3)
      ACC_H(v4, w4) ACC_H(v5, w5) ACC_H(v6, w6) ACC_H(v7, w7)
    }
    for (; j < cnt; ++j){
      int s = __shfl(mc, j, 32);
      float w = __shfl(mw, j, 32);
      uint2 v = U2[(size_t)s*32 + l5];
      ACC_H(v, w)
    }
#undef ACC_H
  }
  int c0 = boff + (l5 << 2);
  float ht[4]; float av[4] = {a.x, a.y, a.z, a.w};
#pragma unroll
  for (int i=0;i<4;++i){
    float b1 = fl ? ((const float*)bx)[c0+i] : bf2f(((const unsigned short*)bx)[c0+i]);
    float b2 = fl ? ((const float*)bh)[c0+i] : bf2f(((const unsigned short*)bh)[c0+i]);
    ht[i] = tanh_fast(di*av[i] + fin(b1) + fin(b2));
  }
  uint2 zv = ((const uint2*)zbuf)[(size_t)d*32 + l5];
  float2 z01 = up2(zv.x), z23 = up2(zv.y);
  float4 hv = ((const float4*)hl)[(size_t)d*32 + l5];
  float hn0 = z01.x*hv.x + (1.0f - z01.x)*ht[0];
  float hn1 = z01.y*hv.y + (1.0f - z01.y)*ht[1];
  float hn2 = z23.x*hv.z + (1.0f - z23.x)*ht[2];
  float hn3 = z23.y*hv.w + (1.0f - z23.y)*ht[3];
  ((float4*)hl)[(size_t)d*32 + l5] = float4{hn0, hn1, hn2, hn3};
  if (has_out){
    if (fl){
      float* op = (float*)outbase + out_off;
      ((float4*)op)[(size_t)d*32 + l5] = float4{hn0, hn1, hn2, hn3};
    } else {
      unsigned short* op = (unsigned short*)outbase + out_off;
      uint2 o;
      o.x = (unsigned)f2bf(hn0) | ((unsigned)f2bf(hn1) << 16);
      o.y = (unsigned)f2bf(hn2) | ((unsigned)f2bf(hn3) << 16);
      ((uint2*)op)[(size_t)d*32 + l5] = o;
    }
  }
}

// ---------------- orchestration ----------------
extern "C" void kernel_launch(void* const* d_in, const int* in_sizes, int n_in,
                              void* d_out, int out_size, void* d_ws, size_t ws_size,
                              hipStream_t stream)
{
  const void* x  = d_in[0];
  const void* h0 = d_in[1];
  const int* ei  = (const int*)d_in[2];
  const void* Wm[6] = { d_in[3], d_in[4], d_in[5], d_in[6], d_in[7], d_in[8] };
  const void* bxz = d_in[9];
  const void* bhz = d_in[10];
  const void* bxr = d_in[11];
  const void* bhr = d_in[12];
  const void* bxh = d_in[13];
  const void* bhh = d_in[14];

  char* wp_ = (char*)d_ws;
  auto alloc = [&](size_t b)->char*{ char* p = wp_; wp_ += (b + 255) & ~(size_t)255; return p; };
  int*   flag  = (int*)alloc(256);
  float* dinv  = (float*)alloc((size_t)NN*4);
  int*   counts= (int*)alloc((size_t)NN*4);
  int*   rowptr= (int*)alloc((size_t)(NN+1)*4);
  int*   cursor= (int*)alloc((size_t)NN*4);
  int*   part  = (int*)alloc(1024);
  int*   pscan = (int*)alloc(1024);
  int2*  ew    = (int2*)alloc((size_t)EE*8);             // 6.4 MB (col, w)
  unsigned short* Wt_hi = (unsigned short*)alloc((size_t)12*16384*2);
  unsigned short* Wt_lo = (unsigned short*)alloc((size_t)12*16384*2);
  float*   h     = (float*)alloc((size_t)LL*NN*HH*4);    // 51.2 MB
  unsigned char* Uzr8 = (unsigned char*)alloc((size_t)NN*256); // 12.8 MB fp8 (z|r)
  __half*  Uh    = (__half*)alloc((size_t)NN*HH*2);      // 12.8 MB
  __half2* zbuf  = (__half2*)alloc((size_t)NN*HH*2);     // 12.8 MB
  __half2* rhbuf = (__half2*)alloc((size_t)NN*HH*2);     // 12.8 MB

  k_detect<<<1, 256, 0, stream>>>((const unsigned short*)x, flag);
  hipMemsetAsync(counts, 0, (size_t)NN*4, stream);
  hipMemsetAsync(ew, 0, (size_t)EE*8, stream);
  k_hist<<<(EE+255)/256, 256, 0, stream>>>(ei, counts, EE);
  k_dinv<<<(NN+255)/256, 256, 0, stream>>>(counts, dinv, NN);
  k_reduce<<<196, 256, 0, stream>>>(counts, part, NN);
  k_scan_partials<<<1, 256, 0, stream>>>(part, pscan, 196, rowptr, NN, EE);
  k_scan_final<<<196, 256, 0, stream>>>(counts, pscan, rowptr, cursor, NN);
  k_fill<<<(EE+255)/256, 256, 0, stream>>>(ei, ei+EE, cursor, dinv, ew, EE);
  k_h0<<<(LL*NN*HH+255)/256, 256, 0, stream>>>(h0, h, flag, LL*NN*HH);
  k_transpose<<<dim3(64,12), 256, 0, stream>>>(Wm[0],Wm[1],Wm[2],Wm[3],Wm[4],Wm[5],
                                               Wt_hi, Wt_lo, flag);

  const int gx = (NN + 127) / 128;   // 391
  const int pg = NN / 8;             // 6250 (two nodes per wave, 4 waves/block)
  for (int t=0; t<TT; ++t){
    for (int l=0; l<LL; ++l){
      const void* S1 = (l==0) ? x : (const void*)h;
      long s1_off = (l==0) ? (long)t*NN*HH : 0;
      int s1_is_x = (l==0) ? 1 : 0;
      float* hl = h + (size_t)l*NN*HH;
      // z + r gates in one GEMM + one propagation pass (fp8 gather buffer)
      gemm_zr<<<gx, 256, 0, stream>>>(S1, s1_off, s1_is_x, hl,
          Wt_hi + (0*2+l)*16384, Wt_hi + (1*2+l)*16384,
          Wt_lo + (0*2+l)*16384, Wt_lo + (1*2+l)*16384,
          Wt_hi + (2*2+l)*16384, Wt_hi + (3*2+l)*16384,
          Wt_lo + (2*2+l)*16384, Wt_lo + (3*2+l)*16384,
          Uzr8, NN, flag);
      prop_zr<<<pg, 256, 0, stream>>>(Uzr8, rowptr, ew, dinv,
          bxz, bhz, bxr, bhr, l*HH, hl, zbuf, rhbuf, flag, NN);
      // candidate + state update (fp16 gather buffer — accuracy-critical path)
      gemm_h<<<gx, 256, 0, stream>>>(S1, s1_off, s1_is_x, (const __half*)rhbuf,
          Wt_hi + (4*2+l)*16384, Wt_hi + (5*2+l)*16384,
          Wt_lo + (4*2+l)*16384, Wt_lo + (5*2+l)*16384, Uh, NN, flag);
      prop_h<<<pg, 256, 0, stream>>>(Uh, rowptr, ew, dinv,
          bxh, bhh, l*HH, zbuf, hl,
          d_out, (long)t*NN*HH, (l==LL-1) ? 1 : 0, flag, NN);
    }
  }
}

// Round 5
// 3500.642 us; speedup vs baseline: 1.3535x; 1.3535x over previous
//
#include <hip/hip_runtime.h>
#include <hip/hip_fp16.h>

#define TT 8
#define NN 50000
#define EE 800000
#define HH 128
#define LL 2

typedef __attribute__((ext_vector_type(8))) short short8_t;
typedef __attribute__((ext_vector_type(4))) float f32x4;
typedef __attribute__((ext_vector_type(2))) float f32x2;

__device__ __forceinline__ float bf2f(unsigned short b){ return __uint_as_float(((unsigned)b)<<16); }
__device__ __forceinline__ unsigned short f2bf(float f){
  unsigned u = __float_as_uint(f);
  u += 0x7fffu + ((u>>16)&1u);
  return (unsigned short)(u>>16);
}
__device__ __forceinline__ float fin(float v){
  return (v == v && fabsf(v) < 1e30f) ? v : 0.0f;   // NaN/Inf -> 0
}
__device__ __forceinline__ float sigm(float x){ return 1.0f/(1.0f+__expf(-x)); }
__device__ __forceinline__ float tanh_fast(float x){
  float t = __expf(-2.0f*fabsf(x));
  float r = (1.0f-t)/(1.0f+t);
  return copysignf(r,x);
}
__device__ __forceinline__ float2 up2(unsigned v){
  __half2 a = *(__half2*)&v;
  return __half22float2(a);
}
__device__ __forceinline__ unsigned packh2(float a, float b){
  __half2 h; h.x = __float2half_rn(a); h.y = __float2half_rn(b);
  return *(unsigned*)&h;
}
// fp8 e4m3 (OCP) helpers — hardware cvt on gfx950
__device__ __forceinline__ float4 up4_fp8(unsigned v){
  f32x2 lo = __builtin_amdgcn_cvt_pk_f32_fp8(v, false);   // bytes 0,1
  f32x2 hi = __builtin_amdgcn_cvt_pk_f32_fp8(v, true);    // bytes 2,3
  return float4{lo[0], lo[1], hi[0], hi[1]};
}
__device__ __forceinline__ unsigned char f2fp8(float v){
  int w = __builtin_amdgcn_cvt_pk_fp8_f32(v, v, 0, false);
  return (unsigned char)(w & 0xFF);
}

// ---------------- dtype detection ----------------
__global__ void k_detect(const unsigned short* __restrict__ xr, int* __restrict__ flag){
  __shared__ int sm[256];
  int bad = 0;
  for (int i = threadIdx.x; i < 4096; i += 256){
    float v = bf2f(xr[i]);
    if (!(fabsf(v) < 64.0f)) bad++;
  }
  sm[threadIdx.x] = bad; __syncthreads();
  for (int off=128; off>0; off>>=1){
    if (threadIdx.x < off) sm[threadIdx.x] += sm[threadIdx.x+off];
    __syncthreads();
  }
  if (threadIdx.x == 0) flag[0] = (sm[0] > 8) ? 1 : 0;
}

// ---------------- CSR build ----------------
__global__ void k_hist(const int* __restrict__ row, int* __restrict__ counts, int E){
  int e = blockIdx.x*256 + threadIdx.x;
  if (e < E){
    int r = row[e];
    if ((unsigned)r < (unsigned)NN) atomicAdd(&counts[r], 1);
  }
}
__global__ void k_dinv(const int* __restrict__ counts, float* __restrict__ dinv, int N){
  int i = blockIdx.x*256 + threadIdx.x;
  if (i < N) dinv[i] = rsqrtf((float)counts[i] + 2.0f);
}
__global__ void k_reduce(const int* __restrict__ counts, int* __restrict__ part, int N){
  __shared__ int sm[256];
  int i = blockIdx.x*256 + threadIdx.x;
  sm[threadIdx.x] = (i < N) ? counts[i] : 0;
  __syncthreads();
  for (int off=128; off>0; off>>=1){
    if (threadIdx.x < off) sm[threadIdx.x] += sm[threadIdx.x+off];
    __syncthreads();
  }
  if (threadIdx.x == 0) part[blockIdx.x] = sm[0];
}
__global__ void k_scan_partials(const int* __restrict__ part, int* __restrict__ pscan,
                                int nb, int* __restrict__ rowptr, int N, int E){
  __shared__ int sm[256];
  int t = threadIdx.x;
  int v = (t < nb) ? part[t] : 0;
  sm[t] = v; __syncthreads();
  for (int off=1; off<256; off<<=1){
    int x = (t >= off) ? sm[t-off] : 0;
    __syncthreads();
    sm[t] += x;
    __syncthreads();
  }
  if (t < nb) pscan[t] = sm[t] - v;
  if (t == 0) rowptr[N] = E;
}
__global__ void k_scan_final(const int* __restrict__ counts, const int* __restrict__ pscan,
                             int* __restrict__ rowptr, int* __restrict__ cursor, int N){
  __shared__ int sm[256];
  int t = threadIdx.x;
  int i = blockIdx.x*256 + t;
  int v = (i < N) ? counts[i] : 0;
  sm[t] = v; __syncthreads();
  for (int off=1; off<256; off<<=1){
    int x = (t >= off) ? sm[t-off] : 0;
    __syncthreads();
    sm[t] += x;
    __syncthreads();
  }
  int ex = sm[t] - v + pscan[blockIdx.x];
  if (i < N){ rowptr[i] = ex; cursor[i] = ex; }
}
__global__ void k_fill(const int* __restrict__ row, const int* __restrict__ col,
                       int* __restrict__ cursor, const float* __restrict__ dinv,
                       int2* __restrict__ ew, int E){
  int e = blockIdx.x*256 + threadIdx.x;
  if (e < E){
    int r = row[e];
    if ((unsigned)r >= (unsigned)NN) return;
    int p = atomicAdd(&cursor[r], 1);
    if ((unsigned)p >= (unsigned)EE) return;
    int c = col[e];
    if ((unsigned)c >= (unsigned)NN) c = 0;
    ew[p] = make_int2(c, __float_as_int(dinv[c]));
  }
}
__global__ void k_h0(const void* __restrict__ h0, float* __restrict__ h,
                     const int* __restrict__ flag, int n){
  const int fl = *flag;
  int i = blockIdx.x*256 + threadIdx.x;
  if (i < n){
    float v = fl ? ((const float*)h0)[i] : bf2f(((const unsigned short*)h0)[i]);
    h[i] = fin(v);
  }
}
__global__ void k_transpose(const void* W0, const void* W1, const void* W2,
                            const void* W3, const void* W4, const void* W5,
                            unsigned short* __restrict__ Wt_hi,
                            unsigned short* __restrict__ Wt_lo,
                            const int* __restrict__ flag){
  const int fl = *flag;
  int mat = blockIdx.y;            // w*2 + l
  int wsel = mat >> 1, l = mat & 1;
  const void* W;
  switch (wsel){
    case 0: W = W0; break; case 1: W = W1; break; case 2: W = W2; break;
    case 3: W = W3; break; case 4: W = W4; break; default: W = W5; break;
  }
  int idx = blockIdx.x*256 + threadIdx.x;   // n*128 + k
  int n = idx >> 7, k = idx & 127;
  size_t src = (size_t)l*16384 + (size_t)k*128 + n;
  float v = fl ? ((const float*)W)[src] : bf2f(((const unsigned short*)W)[src]);
  v = fin(v);
  unsigned short hi = f2bf(v);
  unsigned short lo = f2bf(v - bf2f(hi));
  Wt_hi[(size_t)mat*16384 + idx] = hi;
  Wt_lo[(size_t)mat*16384 + idx] = lo;
}

// ---------------- fused z+r dual-gate GEMM -> interleaved fp8 Uzr8[N][256] ----------------
__global__ __launch_bounds__(256) void gemm_zr(
    const void* __restrict__ S1, long s1_off, int s1_is_x,
    const float* __restrict__ S2,
    const unsigned short* __restrict__ Wz0, const unsigned short* __restrict__ Wz1,
    const unsigned short* __restrict__ Wz2, const unsigned short* __restrict__ Wz3,
    const unsigned short* __restrict__ Wr0, const unsigned short* __restrict__ Wr1,
    const unsigned short* __restrict__ Wr2, const unsigned short* __restrict__ Wr3,
    unsigned char* __restrict__ Uzr8,
    int M, const int* __restrict__ flag)
{
  __shared__ short Alds[128*72];
  __shared__ short Bz[128*72];
  __shared__ short Br[128*72];
  const int fl = *flag;
  const int s1bf = s1_is_x && !fl;
  const int nit = fl ? 16 : 8;
  const int tid = threadIdx.x;
  const int m0 = blockIdx.x * 128;

  const int lane = tid & 63;
  const int wid  = tid >> 6;
  const int wm = (wid & 1) << 6;
  const int wn = (wid >> 1) << 6;
  const int lrow = lane & 15;
  const int lk   = (lane >> 4) << 3;

  f32x4 az[4][4], ar[4][4];
#pragma unroll
  for (int i=0;i<4;++i)
#pragma unroll
    for (int j=0;j<4;++j){ az[i][j] = f32x4{0.f,0.f,0.f,0.f}; ar[i][j] = f32x4{0.f,0.f,0.f,0.f}; }

  const int mrow = tid >> 1;
  const int hf   = tid & 1;
  int arow_g = m0 + mrow; if (arow_g >= M) arow_g = M-1;

  for (int it=0; it<nit; ++it){
    const int phase = it >> 2;              // 0:(S1,hi) 1:(S2,hi) 2:(S1,lo) 3:(S2,lo)
    const int k0 = (it & 3) * 32;
    const int koff = k0 + hf*16;
    const bool useS1 = (phase & 1) == 0;
    // ---- stage A ----
    {
      unsigned pk[16];
      if (useS1 && s1bf){
        const unsigned short* sp = (const unsigned short*)S1 + s1_off + (size_t)arow_g*HH + koff;
        __align__(16) unsigned short tmp[16];
        *(uint4*)&tmp[0] = ((const uint4*)sp)[0];
        *(uint4*)&tmp[8] = ((const uint4*)sp)[1];
#pragma unroll
        for (int j=0;j<16;++j){
          unsigned short t = tmp[j];
          if ((t & 0x7F80u) == 0x7F80u) t = 0;
          pk[j] = (unsigned)t;
        }
      } else {
        __align__(16) float f[16];
        if (useS1){
          const float* sp = (const float*)S1 + s1_off + (size_t)arow_g*HH + koff;
          *(float4*)&f[0]  = ((const float4*)sp)[0];
          *(float4*)&f[4]  = ((const float4*)sp)[1];
          *(float4*)&f[8]  = ((const float4*)sp)[2];
          *(float4*)&f[12] = ((const float4*)sp)[3];
        } else {
          const float* sp = S2 + (size_t)arow_g*HH + koff;
          *(float4*)&f[0]  = ((const float4*)sp)[0];
          *(float4*)&f[4]  = ((const float4*)sp)[1];
          *(float4*)&f[8]  = ((const float4*)sp)[2];
          *(float4*)&f[12] = ((const float4*)sp)[3];
        }
#pragma unroll
        for (int j=0;j<16;++j){
          float v = fin(f[j]);
          unsigned short hi = f2bf(v);
          unsigned short lo = f2bf(v - bf2f(hi));
          pk[j] = (unsigned)hi | ((unsigned)lo << 16);
        }
      }
      short* arp = &Alds[mrow*72 + hf*32];
#pragma unroll
      for (int q=0;q<4;++q){
        uint4 v; v.x=pk[q*4+0]; v.y=pk[q*4+1]; v.z=pk[q*4+2]; v.w=pk[q*4+3];
        *(uint4*)(void*)(arp + q*8) = v;
      }
    }
    // ---- stage Bz + Br ----
    {
      const unsigned short* wz = (phase==0) ? Wz0 : (phase==1) ? Wz1 : (phase==2) ? Wz2 : Wz3;
      const unsigned short* wr = (phase==0) ? Wr0 : (phase==1) ? Wr1 : (phase==2) ? Wr2 : Wr3;
      const unsigned short* wpz = wz + (size_t)mrow*HH + koff;
      const unsigned short* wpr = wr + (size_t)mrow*HH + koff;
      __align__(16) unsigned short tz[16], tr[16];
      *(uint4*)&tz[0] = ((const uint4*)wpz)[0];
      *(uint4*)&tz[8] = ((const uint4*)wpz)[1];
      *(uint4*)&tr[0] = ((const uint4*)wpr)[0];
      *(uint4*)&tr[8] = ((const uint4*)wpr)[1];
      short* bzp = &Bz[mrow*72 + hf*32];
      short* brp = &Br[mrow*72 + hf*32];
#pragma unroll
      for (int q=0;q<4;++q){
        uint4 vz, vr;
        vz.x = ((unsigned)tz[q*4+0])*0x00010001u; vz.y = ((unsigned)tz[q*4+1])*0x00010001u;
        vz.z = ((unsigned)tz[q*4+2])*0x00010001u; vz.w = ((unsigned)tz[q*4+3])*0x00010001u;
        vr.x = ((unsigned)tr[q*4+0])*0x00010001u; vr.y = ((unsigned)tr[q*4+1])*0x00010001u;
        vr.z = ((unsigned)tr[q*4+2])*0x00010001u; vr.w = ((unsigned)tr[q*4+3])*0x00010001u;
        *(uint4*)(void*)(bzp + q*8) = vz;
        *(uint4*)(void*)(brp + q*8) = vr;
      }
    }
    __syncthreads();
#pragma unroll
    for (int ks=0; ks<2; ++ks){
      short8_t af[4], bz[4], br[4];
#pragma unroll
      for (int mt=0;mt<4;++mt)
        af[mt] = *(const short8_t*)&Alds[(wm + mt*16 + lrow)*72 + ks*32 + lk];
#pragma unroll
      for (int nt=0;nt<4;++nt){
        bz[nt] = *(const short8_t*)&Bz[(wn + nt*16 + lrow)*72 + ks*32 + lk];
        br[nt] = *(const short8_t*)&Br[(wn + nt*16 + lrow)*72 + ks*32 + lk];
      }
#pragma unroll
      for (int mt=0;mt<4;++mt)
#pragma unroll
        for (int nt=0;nt<4;++nt){
          az[mt][nt] = __builtin_amdgcn_mfma_f32_16x16x32_bf16(af[mt], bz[nt], az[mt][nt], 0, 0, 0);
          ar[mt][nt] = __builtin_amdgcn_mfma_f32_16x16x32_bf16(af[mt], br[nt], ar[mt][nt], 0, 0, 0);
        }
    }
    __syncthreads();
  }
#pragma unroll
  for (int mt=0;mt<4;++mt){
    int rbase = m0 + wm + mt*16 + ((lane>>4)<<2);
#pragma unroll
    for (int nt=0;nt<4;++nt){
      int cc = wn + nt*16 + (lane & 15);
      f32x4 vz = az[mt][nt];
      f32x4 vr = ar[mt][nt];
#pragma unroll
      for (int r=0;r<4;++r){
        int row = rbase + r;
        if (row < M){
          Uzr8[(size_t)row*256 + cc]       = f2fp8(vz[r]);
          Uzr8[(size_t)row*256 + 128 + cc] = f2fp8(vr[r]);
        }
      }
    }
  }
}

// ---------------- single-gate GEMM (h-candidate), S2 = fp16 rhbuf ----------------
__global__ __launch_bounds__(256) void gemm_h(
    const void* __restrict__ S1, long s1_off, int s1_is_x,
    const __half* __restrict__ S2,
    const unsigned short* __restrict__ W0, const unsigned short* __restrict__ W1,
    const unsigned short* __restrict__ W2, const unsigned short* __restrict__ W3,
    __half* __restrict__ C, int M, const int* __restrict__ flag)
{
  __shared__ short Alds[128*72];
  __shared__ short Blds[128*72];
  const int fl = *flag;
  const int s1bf = s1_is_x && !fl;
  const int nit = fl ? 16 : 8;
  const int tid = threadIdx.x;
  const int m0 = blockIdx.x * 128;

  const int lane = tid & 63;
  const int wid  = tid >> 6;
  const int wm = (wid & 1) << 6;
  const int wn = (wid >> 1) << 6;
  const int lrow = lane & 15;
  const int lk   = (lane >> 4) << 3;

  f32x4 acc[4][4];
#pragma unroll
  for (int i=0;i<4;++i)
#pragma unroll
    for (int j=0;j<4;++j) acc[i][j] = f32x4{0.f,0.f,0.f,0.f};

  const int mrow = tid >> 1;
  const int hf = tid & 1;
  int arow_g = m0 + mrow; if (arow_g >= M) arow_g = M-1;

  for (int it=0; it<nit; ++it){
    const int phase = it >> 2;
    const int k0 = (it & 3) * 32;
    const int koff = k0 + hf*16;
    const bool useS1 = (phase & 1) == 0;
    {
      unsigned pk[16];
      if (useS1 && s1bf){
        const unsigned short* sp = (const unsigned short*)S1 + s1_off + (size_t)arow_g*HH + koff;
        __align__(16) unsigned short tmp[16];
        *(uint4*)&tmp[0] = ((const uint4*)sp)[0];
        *(uint4*)&tmp[8] = ((const uint4*)sp)[1];
#pragma unroll
        for (int j=0;j<16;++j){
          unsigned short t = tmp[j];
          if ((t & 0x7F80u) == 0x7F80u) t = 0;
          pk[j] = (unsigned)t;
        }
      } else {
        __align__(16) float f[16];
        if (useS1){
          const float* sp = (const float*)S1 + s1_off + (size_t)arow_g*HH + koff;
          *(float4*)&f[0]  = ((const float4*)sp)[0];
          *(float4*)&f[4]  = ((const float4*)sp)[1];
          *(float4*)&f[8]  = ((const float4*)sp)[2];
          *(float4*)&f[12] = ((const float4*)sp)[3];
        } else {
          const __half* sp = S2 + (size_t)arow_g*HH + koff;
          __align__(16) __half tmp[16];
          *(uint4*)&tmp[0] = ((const uint4*)sp)[0];
          *(uint4*)&tmp[8] = ((const uint4*)sp)[1];
#pragma unroll
          for (int j=0;j<16;++j) f[j] = __half2float(tmp[j]);
        }
#pragma unroll
        for (int j=0;j<16;++j){
          float v = fin(f[j]);
          unsigned short hi = f2bf(v);
          unsigned short lo = f2bf(v - bf2f(hi));
          pk[j] = (unsigned)hi | ((unsigned)lo << 16);
        }
      }
      short* arp = &Alds[mrow*72 + hf*32];
#pragma unroll
      for (int q=0;q<4;++q){
        uint4 v; v.x=pk[q*4+0]; v.y=pk[q*4+1]; v.z=pk[q*4+2]; v.w=pk[q*4+3];
        *(uint4*)(void*)(arp + q*8) = v;
      }
    }
    {
      const unsigned short* wb = (phase==0) ? W0 : (phase==1) ? W1 : (phase==2) ? W2 : W3;
      const unsigned short* wp = wb + (size_t)mrow*HH + koff;
      __align__(16) unsigned short tb[16];
      *(uint4*)&tb[0] = ((const uint4*)wp)[0];
      *(uint4*)&tb[8] = ((const uint4*)wp)[1];
      unsigned pb[16];
#pragma unroll
      for (int j=0;j<16;++j) pb[j] = ((unsigned)tb[j]) * 0x00010001u;
      short* brp = &Blds[mrow*72 + hf*32];
#pragma unroll
      for (int q=0;q<4;++q){
        uint4 v; v.x=pb[q*4+0]; v.y=pb[q*4+1]; v.z=pb[q*4+2]; v.w=pb[q*4+3];
        *(uint4*)(void*)(brp + q*8) = v;
      }
    }
    __syncthreads();
#pragma unroll
    for (int ks=0; ks<2; ++ks){
      short8_t af[4], bfr[4];
#pragma unroll
      for (int mt=0;mt<4;++mt)
        af[mt] = *(const short8_t*)&Alds[(wm + mt*16 + lrow)*72 + ks*32 + lk];
#pragma unroll
      for (int nt=0;nt<4;++nt)
        bfr[nt] = *(const short8_t*)&Blds[(wn + nt*16 + lrow)*72 + ks*32 + lk];
#pragma unroll
      for (int mt=0;mt<4;++mt)
#pragma unroll
        for (int nt=0;nt<4;++nt)
          acc[mt][nt] = __builtin_amdgcn_mfma_f32_16x16x32_bf16(af[mt], bfr[nt], acc[mt][nt], 0, 0, 0);
    }
    __syncthreads();
  }
#pragma unroll
  for (int mt=0;mt<4;++mt){
    int rbase = m0 + wm + mt*16 + ((lane>>4)<<2);
#pragma unroll
    for (int nt=0;nt<4;++nt){
      int cc = wn + nt*16 + (lane & 15);
      f32x4 a = acc[mt][nt];
#pragma unroll
      for (int r=0;r<4;++r){
        int row = rbase + r;
        if (row < M) C[(size_t)row*HH + cc] = __float2half_rn(a[r]);
      }
    }
  }
}

// ---------------- fused z+r propagation (one wave per dst node, fp8 gather) ----------------
// Uzr8: [N][256] fp8 = z|r interleaved. Lane L owns channels 4L..4L+3
// (z-channels for L<32, r-channels 4(L-32).. for L>=32).
// 16-deep masked gather batches: pad lanes carry (col=0, w=0) so every batch
// is full-width -> ONE latency exposure per 16 edges, no scalar tail.
__global__ __launch_bounds__(256) void prop_zr(
    const unsigned char* __restrict__ Uzr8,
    const int* __restrict__ rowptr, const int2* __restrict__ ew,
    const float* __restrict__ dinv,
    const void* __restrict__ bxz, const void* __restrict__ bhz,
    const void* __restrict__ bxr, const void* __restrict__ bhr, int boff,
    const float* __restrict__ hl, __half2* __restrict__ zbuf,
    __half2* __restrict__ rhbuf, const int* __restrict__ flag, int N)
{
  const int fl = *flag;
  int lane = threadIdx.x & 63;
  int d = (blockIdx.x << 2) + (threadIdx.x >> 6);
  if (d >= N) return;
  float di = dinv[d];
  int l5 = lane & 31;
  int c = boff + (l5 << 2);
  // hoisted epilogue operands (latency hides under gather loop)
  const void* bx_p = (lane < 32) ? bxz : bxr;
  const void* bh_p = (lane < 32) ? bhz : bhr;
  float bs0, bs1, bs2, bs3;
  {
    float a0_ = fl ? ((const float*)bx_p)[c+0] : bf2f(((const unsigned short*)bx_p)[c+0]);
    float a1_ = fl ? ((const float*)bx_p)[c+1] : bf2f(((const unsigned short*)bx_p)[c+1]);
    float a2_ = fl ? ((const float*)bx_p)[c+2] : bf2f(((const unsigned short*)bx_p)[c+2]);
    float a3_ = fl ? ((const float*)bx_p)[c+3] : bf2f(((const unsigned short*)bx_p)[c+3]);
    float b0_ = fl ? ((const float*)bh_p)[c+0] : bf2f(((const unsigned short*)bh_p)[c+0]);
    float b1_ = fl ? ((const float*)bh_p)[c+1] : bf2f(((const unsigned short*)bh_p)[c+1]);
    float b2_ = fl ? ((const float*)bh_p)[c+2] : bf2f(((const unsigned short*)bh_p)[c+2]);
    float b3_ = fl ? ((const float*)bh_p)[c+3] : bf2f(((const unsigned short*)bh_p)[c+3]);
    bs0 = fin(a0_) + fin(b0_); bs1 = fin(a1_) + fin(b1_);
    bs2 = fin(a2_) + fin(b2_); bs3 = fin(a3_) + fin(b3_);
  }
  float4 hv = ((const float4*)hl)[(size_t)d*32 + l5];   // used by r-half
  const unsigned* U1 = (const unsigned*)Uzr8;   // 64 uints per row (4 fp8 each)
  unsigned sv = U1[(size_t)d*64 + lane];
  float4 sf = up4_fp8(sv);
  float sw = 2.0f*di;
  float4 a0 = float4{sw*sf.x, sw*sf.y, sw*sf.z, sw*sf.w};
  float4 a1 = float4{0.f,0.f,0.f,0.f};
  int b = rowptr[d], e = rowptr[d+1];
  if (b < 0) b = 0; if (e > EE) e = EE; if (e < b) e = b;
  for (int base=b; base<e; base+=64){
    int cnt = e - base; if (cnt > 64) cnt = 64;
    int idx = base + lane;
    int2 ev = (idx < e) ? ew[idx] : make_int2(0,0);
    int mc = ev.x; float mw = __int_as_float(ev.y);
    if ((unsigned)mc >= (unsigned)NN){ mc = 0; mw = 0.0f; }
    for (int j=0; j<cnt; j+=16){
      int ss[16]; float ww[16]; unsigned vv[16];
#pragma unroll
      for (int q=0;q<16;++q){ ss[q] = __shfl(mc, j+q); ww[q] = __shfl(mw, j+q); }
#pragma unroll
      for (int q=0;q<16;++q){ vv[q] = U1[(size_t)ss[q]*64 + lane]; }
#pragma unroll
      for (int q=0;q<16;q+=2){
        float4 g0 = up4_fp8(vv[q]);
        a0.x += ww[q]*g0.x; a0.y += ww[q]*g0.y; a0.z += ww[q]*g0.z; a0.w += ww[q]*g0.w;
        float4 g1 = up4_fp8(vv[q+1]);
        a1.x += ww[q+1]*g1.x; a1.y += ww[q+1]*g1.y; a1.z += ww[q+1]*g1.z; a1.w += ww[q+1]*g1.w;
      }
    }
  }
  float4 a = float4{a0.x+a1.x, a0.y+a1.y, a0.z+a1.z, a0.w+a1.w};
  float g0 = sigm(di*a.x + bs0);
  float g1 = sigm(di*a.y + bs1);
  float g2 = sigm(di*a.z + bs2);
  float g3 = sigm(di*a.w + bs3);
  if (lane < 32){
    uint2 o; o.x = packh2(g0, g1); o.y = packh2(g2, g3);
    ((uint2*)zbuf)[(size_t)d*32 + l5] = o;
  } else {
    uint2 o; o.x = packh2(g0*hv.x, g1*hv.y); o.y = packh2(g2*hv.z, g3*hv.w);
    ((uint2*)rhbuf)[(size_t)d*32 + l5] = o;
  }
}

// ---------------- h-candidate propagation + state update ----------------
__global__ __launch_bounds__(256) void prop_h(
    const __half* __restrict__ U, const int* __restrict__ rowptr,
    const int2* __restrict__ ew, const float* __restrict__ dinv,
    const void* __restrict__ bx, const void* __restrict__ bh, int boff,
    const __half2* __restrict__ zbuf, float* __restrict__ hl,
    void* __restrict__ outbase, long out_off, int has_out,
    const int* __restrict__ flag, int N)
{
  const int fl = *flag;
  int lane = threadIdx.x & 63;
  int d = (blockIdx.x << 2) + (threadIdx.x >> 6);
  if (d >= N) return;
  float di = dinv[d];
  int c = boff + (lane << 1);
  float bs0, bs1;
  {
    float a0_ = fl ? ((const float*)bx)[c]   : bf2f(((const unsigned short*)bx)[c]);
    float a1_ = fl ? ((const float*)bx)[c+1] : bf2f(((const unsigned short*)bx)[c+1]);
    float b0_ = fl ? ((const float*)bh)[c]   : bf2f(((const unsigned short*)bh)[c]);
    float b1_ = fl ? ((const float*)bh)[c+1] : bf2f(((const unsigned short*)bh)[c+1]);
    bs0 = fin(a0_) + fin(b0_); bs1 = fin(a1_) + fin(b1_);
  }
  __half2 zv2 = zbuf[(size_t)d*64 + lane];
  float z0 = __half2float(zv2.x), z1 = __half2float(zv2.y);
  float2 hv = ((const float2*)hl)[(size_t)d*64 + lane];
  const unsigned* U1 = (const unsigned*)U;   // half2 per lane, 64 per row
  float2 sf = up2(U1[(size_t)d*64 + lane]);
  float sw = 2.0f*di;
  float2 a0 = float2{sw*sf.x, sw*sf.y};
  float2 a1 = float2{0.f, 0.f};
  int b = rowptr[d], e = rowptr[d+1];
  if (b < 0) b = 0; if (e > EE) e = EE; if (e < b) e = b;
  for (int base=b; base<e; base+=64){
    int cnt = e - base; if (cnt > 64) cnt = 64;
    int idx = base + lane;
    int2 ev = (idx < e) ? ew[idx] : make_int2(0,0);
    int mc = ev.x; float mw = __int_as_float(ev.y);
    if ((unsigned)mc >= (unsigned)NN){ mc = 0; mw = 0.0f; }
    for (int j=0; j<cnt; j+=16){
      int ss[16]; float ww[16]; unsigned vv[16];
#pragma unroll
      for (int q=0;q<16;++q){ ss[q] = __shfl(mc, j+q); ww[q] = __shfl(mw, j+q); }
#pragma unroll
      for (int q=0;q<16;++q){ vv[q] = U1[(size_t)ss[q]*64 + lane]; }
#pragma unroll
      for (int q=0;q<16;q+=2){
        float2 g0 = up2(vv[q]);
        a0.x += ww[q]*g0.x; a0.y += ww[q]*g0.y;
        float2 g1 = up2(vv[q+1]);
        a1.x += ww[q+1]*g1.x; a1.y += ww[q+1]*g1.y;
      }
    }
  }
  float ax = a0.x + a1.x, ay = a0.y + a1.y;
  float ht0 = tanh_fast(di*ax + bs0);
  float ht1 = tanh_fast(di*ay + bs1);
  float hn0 = z0*hv.x + (1.0f - z0)*ht0;
  float hn1 = z1*hv.y + (1.0f - z1)*ht1;
  ((float2*)hl)[(size_t)d*64 + lane] = float2{hn0, hn1};
  if (has_out){
    if (fl){
      float* op = (float*)outbase + out_off;
      ((float2*)op)[(size_t)d*64 + lane] = float2{hn0, hn1};
    } else {
      unsigned short* op = (unsigned short*)outbase + out_off;
      ((unsigned int*)op)[(size_t)d*64 + lane] =
          (unsigned)f2bf(hn0) | ((unsigned)f2bf(hn1) << 16);
    }
  }
}

// ---------------- orchestration ----------------
extern "C" void kernel_launch(void* const* d_in, const int* in_sizes, int n_in,
                              void* d_out, int out_size, void* d_ws, size_t ws_size,
                              hipStream_t stream)
{
  const void* x  = d_in[0];
  const void* h0 = d_in[1];
  const int* ei  = (const int*)d_in[2];
  const void* Wm[6] = { d_in[3], d_in[4], d_in[5], d_in[6], d_in[7], d_in[8] };
  const void* bxz = d_in[9];
  const void* bhz = d_in[10];
  const void* bxr = d_in[11];
  const void* bhr = d_in[12];
  const void* bxh = d_in[13];
  const void* bhh = d_in[14];

  char* wp_ = (char*)d_ws;
  auto alloc = [&](size_t b)->char*{ char* p = wp_; wp_ += (b + 255) & ~(size_t)255; return p; };
  int*   flag  = (int*)alloc(256);
  float* dinv  = (float*)alloc((size_t)NN*4);
  int*   counts= (int*)alloc((size_t)NN*4);
  int*   rowptr= (int*)alloc((size_t)(NN+1)*4);
  int*   cursor= (int*)alloc((size_t)NN*4);
  int*   part  = (int*)alloc(1024);
  int*   pscan = (int*)alloc(1024);
  int2*  ew    = (int2*)alloc((size_t)EE*8);             // 6.4 MB (col, w)
  unsigned short* Wt_hi = (unsigned short*)alloc((size_t)12*16384*2);
  unsigned short* Wt_lo = (unsigned short*)alloc((size_t)12*16384*2);
  float*   h     = (float*)alloc((size_t)LL*NN*HH*4);    // 51.2 MB
  unsigned char* Uzr8 = (unsigned char*)alloc((size_t)NN*256); // 12.8 MB fp8 (z|r)
  __half*  Uh    = (__half*)alloc((size_t)NN*HH*2);      // 12.8 MB
  __half2* zbuf  = (__half2*)alloc((size_t)NN*HH*2);     // 12.8 MB
  __half2* rhbuf = (__half2*)alloc((size_t)NN*HH*2);     // 12.8 MB

  k_detect<<<1, 256, 0, stream>>>((const unsigned short*)x, flag);
  hipMemsetAsync(counts, 0, (size_t)NN*4, stream);
  hipMemsetAsync(ew, 0, (size_t)EE*8, stream);
  k_hist<<<(EE+255)/256, 256, 0, stream>>>(ei, counts, EE);
  k_dinv<<<(NN+255)/256, 256, 0, stream>>>(counts, dinv, NN);
  k_reduce<<<196, 256, 0, stream>>>(counts, part, NN);
  k_scan_partials<<<1, 256, 0, stream>>>(part, pscan, 196, rowptr, NN, EE);
  k_scan_final<<<196, 256, 0, stream>>>(counts, pscan, rowptr, cursor, NN);
  k_fill<<<(EE+255)/256, 256, 0, stream>>>(ei, ei+EE, cursor, dinv, ew, EE);
  k_h0<<<(LL*NN*HH+255)/256, 256, 0, stream>>>(h0, h, flag, LL*NN*HH);
  k_transpose<<<dim3(64,12), 256, 0, stream>>>(Wm[0],Wm[1],Wm[2],Wm[3],Wm[4],Wm[5],
                                               Wt_hi, Wt_lo, flag);

  const int gx = (NN + 127) / 128;   // 391
  const int pg = NN / 4;             // 12500
  for (int t=0; t<TT; ++t){
    for (int l=0; l<LL; ++l){
      const void* S1 = (l==0) ? x : (const void*)h;
      long s1_off = (l==0) ? (long)t*NN*HH : 0;
      int s1_is_x = (l==0) ? 1 : 0;
      float* hl = h + (size_t)l*NN*HH;
      // z + r gates in one GEMM + one propagation pass (fp8 gather buffer)
      gemm_zr<<<gx, 256, 0, stream>>>(S1, s1_off, s1_is_x, hl,
          Wt_hi + (0*2+l)*16384, Wt_hi + (1*2+l)*16384,
          Wt_lo + (0*2+l)*16384, Wt_lo + (1*2+l)*16384,
          Wt_hi + (2*2+l)*16384, Wt_hi + (3*2+l)*16384,
          Wt_lo + (2*2+l)*16384, Wt_lo + (3*2+l)*16384,
          Uzr8, NN, flag);
      prop_zr<<<pg, 256, 0, stream>>>(Uzr8, rowptr, ew, dinv,
          bxz, bhz, bxr, bhr, l*HH, hl, zbuf, rhbuf, flag, NN);
      // candidate + state update (fp16 gather buffer — accuracy-critical path)
      gemm_h<<<gx, 256, 0, stream>>>(S1, s1_off, s1_is_x, (const __half*)rhbuf,
          Wt_hi + (4*2+l)*16384, Wt_hi + (5*2+l)*16384,
          Wt_lo + (4*2+l)*16384, Wt_lo + (5*2+l)*16384, Uh, NN, flag);
      prop_h<<<pg, 256, 0, stream>>>(Uh, rowptr, ew, dinv,
          bxh, bhh, l*HH, zbuf, hl,
          d_out, (long)t*NN*HH, (l==LL-1) ? 1 : 0, flag, NN);
    }
  }
}